// Round 6
// baseline (383.174 us; speedup 1.0000x reference)
//
#include <hip/hip_runtime.h>

typedef float f4 __attribute__((ext_vector_type(4)));
typedef short s8 __attribute__((ext_vector_type(8)));
typedef unsigned short u16x4 __attribute__((ext_vector_type(4)));
typedef unsigned short u16x8 __attribute__((ext_vector_type(8)));

// ---- ws layout (bytes) ----
// embB   : 1 MiB    .. 5 MiB   (4096*512 bf16)
// rbT    : 5 MiB    .. 37 MiB  (64*512*512 bf16, [n][o][i])
// gemmT  : 37 MiB   .. 53 MiB  (2 slices of 4096*512 f32, [b][o])

__device__ __forceinline__ unsigned short f2bf(float f) {
    unsigned int u = __float_as_uint(f);
    unsigned int r = (u + 0x7fffu + ((u >> 16) & 1u)) >> 16;
    return (unsigned short)r;
}

// blocks [0,1024): rbT transpose, one block per (n, o-tile, i-half); 4 i-tiles each,
// double-buffered LDS. blocks [1024, 3072): emb f32->bf16.  (unchanged from R5)
__global__ __launch_bounds__(256) void prep_kernel(const float* __restrict__ emb,
                                                   unsigned short* __restrict__ embB,
                                                   const float* __restrict__ rb,
                                                   unsigned short* __restrict__ rbT) {
    int bid = blockIdx.x;
    int t = threadIdx.x;
    if (bid >= 1024) {
        int g = ((bid - 1024) * 256 + t) * 4;
        f4 v = *(const f4*)(emb + g);
        u16x4 o;
        o[0] = f2bf(v[0]); o[1] = f2bf(v[1]); o[2] = f2bf(v[2]); o[3] = f2bf(v[3]);
        *(u16x4*)(embB + g) = o;
        return;
    }
    __shared__ float tl[2][64][65];
    int n = bid >> 4;
    int sub = bid & 15;
    int o0 = (sub & 7) * 64;
    int ibase = (sub >> 3) * 4;            // i-tile range [ibase, ibase+4)
    int oq = t & 15, ir = t >> 4;          // load-phase index
    int ic = t & 7, or0 = t >> 3;          // write-phase index
    const float* rbn = rb + (size_t)n * 262144;
    unsigned short* rbTn = rbT + (size_t)n * 262144;

    f4 v[4];
#pragma unroll
    for (int k = 0; k < 4; k++)
        v[k] = *(const f4*)(rbn + (size_t)(ibase * 64 + ir + 16 * k) * 512 + o0 + oq * 4);

    for (int jj = 0; jj < 4; jj++) {
        int ii = ibase + jj;
        int buf = jj & 1;
#pragma unroll
        for (int k = 0; k < 4; k++) {
            int r = ir + 16 * k;
            tl[buf][r][oq * 4 + 0] = v[k][0]; tl[buf][r][oq * 4 + 1] = v[k][1];
            tl[buf][r][oq * 4 + 2] = v[k][2]; tl[buf][r][oq * 4 + 3] = v[k][3];
        }
        if (jj < 3) {
            int i0n = (ii + 1) * 64;
#pragma unroll
            for (int k = 0; k < 4; k++)
                v[k] = *(const f4*)(rbn + (size_t)(i0n + ir + 16 * k) * 512 + o0 + oq * 4);
        }
        __syncthreads();
        int i0 = ii * 64;
#pragma unroll
        for (int k = 0; k < 2; k++) {
            int orow = or0 + 32 * k;
            u16x8 w;
#pragma unroll
            for (int j = 0; j < 8; j++) w[j] = f2bf(tl[buf][ic * 8 + j][orow]);
            *(u16x8*)(rbTn + (size_t)(o0 + orow) * 512 + i0 + ic * 8) = w;
        }
    }
}

// Main fused GEMM, v6: NO LDS A-path.
// Diagnosis (R0-R5): per wave-iter the old structure moved ~4KB ds_read + 4KB
// lds-write per 16 MFMA -> ~230 B/cyc/CU LDS demand vs ~85-128 B/cyc ceiling
// (m134). MfmaUtil pinned at 35% across ALL scheduling variants = LDS-BW-bound.
// Staging was wave-private (zero cross-wave reuse) -> LDS was pure overhead.
// Now: A-fragments load global->VGPR directly (L2/L3-resident rbT, XCD-aligned
// o-slices), register double-buffer with distance-1 prefetch, NO barriers, NO
// asm in the K-loop; compiler schedules waits. LDS keeps only attS + epilogue T.
// __launch_bounds__(256,3): VGPR cap ~168 so embF[4][4] (64 VGPR) + aA/aB (32)
// can be truly register-resident (VGPR_Count is the diagnostic; 64 = demoted).
__global__ __launch_bounds__(256, 3) void gemm_fold(const unsigned short* __restrict__ embB,
                                                    const unsigned short* __restrict__ rbT,
                                                    const int* __restrict__ ids,
                                                    const float* __restrict__ rel_att,
                                                    const float* __restrict__ relb,
                                                    float* __restrict__ gemmT) {
    __shared__ float attS[32][64];                // [n][m] broadcast layout
    __shared__ float T[64][68];                   // epilogue transpose tile

    const int t = threadIdx.x;
    const int wv = t >> 6;
    const int ln = t & 63;
    const int q  = ln >> 4;     // quad 0..3
    const int lm = ln & 15;
    const int g  = blockIdx.x;
    const int o0 = (g & 7) * 64;                  // fastest -> XCD-aligned o slice
    const int m0 = ((g >> 3) & 63) * 64;
    const int nz = g >> 9;                        // n-half 0/1
    const int nbase = nz * 32;

    // stage att tile [32 n][64 m], gathered via ids: 8 per thread
#pragma unroll
    for (int k = 0; k < 8; k++) {
        int idx = t + 256 * k;
        int n = idx >> 6, m = idx & 63;
        attS[n][m] = rel_att[(size_t)ids[m0 + m] * 64 + nbase + n];
    }
    __syncthreads();

    // this lane's A-row base: rbT[(n*512 + o0 + wv*16 + lm)*512 + ic*128 + ks*32 + q*8]
    const unsigned short* aBase = rbT + (size_t)(o0 + wv * 16 + lm) * 512 + q * 8
                                      + (size_t)nbase * 262144;

    const f4 z = {0.f, 0.f, 0.f, 0.f};
    f4 acc[4] = {z, z, z, z};
    s8 embF[4][4];
    s8 aA[4], aB[4];

    // preload tile s=0 (n=nbase, ic=0)
#pragma unroll
    for (int ks = 0; ks < 4; ks++)
        aA[ks] = *(const s8*)(aBase + ks * 32);

    // iterate s: MFMA on cur (loaded last iter), prefetch s+1 into nxt.
    auto iterate = [&](int s, s8 (&cur)[4], s8 (&nxt)[4]) {
        const int nl = s & 31;
        if (nl == 0) {
            // emb fragments for this i-chunk: register-resident across the n loop.
            const int ic = s >> 5;
#pragma unroll
            for (int ks = 0; ks < 4; ks++)
#pragma unroll
                for (int ms = 0; ms < 4; ms++)
                    embF[ks][ms] = *(const s8*)(embB + (size_t)(m0 + ms * 16 + lm) * 512
                                                + ic * 128 + ks * 32 + q * 8);
        }
        if (s < 127) {
            const int s1 = s + 1;
            const unsigned short* p = aBase + (size_t)(s1 & 31) * 262144 + (s1 >> 5) * 128;
#pragma unroll
            for (int ks = 0; ks < 4; ks++)
                nxt[ks] = *(const s8*)(p + ks * 32);
        }
        f4 an[4];
#pragma unroll
        for (int ms = 0; ms < 4; ms++)
            an[ms] = __builtin_amdgcn_mfma_f32_16x16x32_bf16(cur[0], embF[0][ms], z, 0, 0, 0);
#pragma unroll
        for (int ks = 1; ks < 4; ks++)
#pragma unroll
            for (int ms = 0; ms < 4; ms++)
                an[ms] = __builtin_amdgcn_mfma_f32_16x16x32_bf16(cur[ks], embF[ks][ms], an[ms], 0, 0, 0);
#pragma unroll
        for (int ms = 0; ms < 4; ms++) {
            float av = attS[nl][ms * 16 + lm];    // 4-way broadcast read
            acc[ms] += av * an[ms];
        }
    };

    for (int s = 0; s < 128; s += 2) {
        iterate(s,     aA, aB);
        iterate(s + 1, aB, aA);
    }

    // bias fold: acc[ms] += sum_{n in half} att(n, m) * relb[nbase+n][o]
    const float* rbb = relb + (size_t)nbase * 512 + o0 + wv * 16 + q * 4;
#pragma unroll 4
    for (int n = 0; n < 32; n++) {
        f4 rb4 = *(const f4*)(rbb + (size_t)n * 512);
#pragma unroll
        for (int ms = 0; ms < 4; ms++)
            acc[ms] += attS[n][ms * 16 + lm] * rb4;
    }

    // transpose epilogue: acc (o-major fragments) -> [b][o] tile via LDS, then
    // coalesced stores.
    __syncthreads();                              // waves drift; order T writes
#pragma unroll
    for (int ms = 0; ms < 4; ms++)
#pragma unroll
        for (int r = 0; r < 4; r++)
            T[ms * 16 + lm][wv * 16 + q * 4 + r] = acc[ms][r];
    __syncthreads();
    float* gB = gemmT + (size_t)nz * 4096 * 512;
    const int mrow = t >> 2;
    const int oc = (t & 3) * 16;
    float* gp = gB + (size_t)(m0 + mrow) * 512 + o0 + oc;
#pragma unroll
    for (int j = 0; j < 4; j++)
        *(f4*)(gp + j * 4) = *(const f4*)(&T[mrow][oc + j * 4]);
}

// LayerNorm over o (512) per b, [b][o] layout: pure-register, no LDS.
// 4 rows per block (64 lanes/row, wave-wide shuffle reduce); grid 1024.
__global__ __launch_bounds__(256) void ln_kernel(const float* __restrict__ g0,
                                                 const float* __restrict__ g1,
                                                 float* __restrict__ out) {
    int t = threadIdx.x;
    int b = blockIdx.x * 4 + (t >> 6);
    int l = t & 63;
    const float* p0 = g0 + (size_t)b * 512 + l * 4;
    const float* p1 = g1 + (size_t)b * 512 + l * 4;
    f4 v[2];
    float s1 = 0.f, s2 = 0.f;
#pragma unroll
    for (int j = 0; j < 2; j++) {
        f4 a = *(const f4*)(p0 + j * 256);
        f4 c = *(const f4*)(p1 + j * 256);
        f4 w = a + c;
        v[j] = w;
        s1 += w[0] + w[1] + w[2] + w[3];
        s2 += w[0] * w[0] + w[1] * w[1] + w[2] * w[2] + w[3] * w[3];
    }
#pragma unroll
    for (int off = 32; off; off >>= 1) {
        s1 += __shfl_xor(s1, off, 64);
        s2 += __shfl_xor(s2, off, 64);
    }
    float mu = s1 * (1.f / 512.f);
    float var = s2 * (1.f / 512.f) - mu * mu;
    float rs = rsqrtf(var + 1e-5f);
    float* po = out + (size_t)b * 512 + l * 4;
#pragma unroll
    for (int j = 0; j < 2; j++) {
        f4 w = (v[j] - mu) * rs;
        *(f4*)(po + j * 256) = w;
    }
}

extern "C" void kernel_launch(void* const* d_in, const int* in_sizes, int n_in,
                              void* d_out, int out_size, void* d_ws, size_t ws_size,
                              hipStream_t stream) {
    (void)in_sizes; (void)n_in; (void)out_size; (void)ws_size;
    const float* emb      = (const float*)d_in[0];
    const int*   proj_ids = (const int*)d_in[1];
    const float* rel_att  = (const float*)d_in[2];
    const float* rel_base = (const float*)d_in[3];
    const float* rel_bias = (const float*)d_in[4];
    float* out = (float*)d_out;

    char* w = (char*)d_ws;
    unsigned short* embB  = (unsigned short*)(w + (1u << 20));
    unsigned short* rbT   = (unsigned short*)(w + 5u * (1u << 20));
    float*          gemmT = (float*)(w + 37u * (1u << 20));   // 2 slices of 8 MiB, [b][o]
    float*          g1    = gemmT + (size_t)4096 * 512;

    prep_kernel<<<dim3(1024 + 2048), dim3(256), 0, stream>>>(emb, embB, rel_base, rbT);
    gemm_fold<<<dim3(1024), dim3(256), 0, stream>>>(embB, rbT, proj_ids, rel_att, rel_bias, gemmT);
    ln_kernel<<<dim3(1024), dim3(256), 0, stream>>>(gemmT, g1, out);
}